// Round 2
// baseline (24568.594 us; speedup 1.0000x reference)
//
#include <hip/hip_runtime.h>
#include <math.h>

#define TC_INf 17.452274f
#define NOT_FIREDf 9999.0f

// Pre-transpose conv2 weights: w2t[((ci*5+ky)*5+kx)*64 + co] = w2[(co*12+ci)*25 + ky*5+kx]
__global__ void w2_transpose_kernel(const float* __restrict__ w2, float* __restrict__ w2t) {
    int idx = blockIdx.x * 256 + threadIdx.x;
    if (idx >= 19200) return;
    int co = idx & 63;
    int r = idx >> 6;          // 0..299 = ci*25 + k
    int ci = r / 25;
    int k = r - ci * 25;
    w2t[r * 64 + co] = w2[(co * 12 + ci) * 25 + k];
}

__launch_bounds__(256)
__global__ void snn_sim_kernel(const float* __restrict__ img,
                               const float* __restrict__ w1g,
                               const float* __restrict__ b1g,
                               const float* __restrict__ b2g,
                               const float* __restrict__ w2raw,
                               const float* __restrict__ w2t,
                               const float* __restrict__ fcw,
                               const float* __restrict__ b3g,
                               float* __restrict__ out,
                               const int use_t) {
    const int bimg = blockIdx.x;
    const int tid = threadIdx.x;
    const int lane = tid & 63;
    const int wv = tid >> 6;   // 4 waves

    __shared__ float v1[6912];             // [c][24][24], v_mem (bias accumulated stepwise)
    __shared__ float v2[4096];             // [oy*8+ox][co] -> contiguous co
    __shared__ float w1s[300];             // [c][ky*5+kx]
    __shared__ unsigned short stin[784];   // input spike time per pixel
    __shared__ unsigned short evin[784];   // this-step input events (pixel idx)
    __shared__ unsigned short ev1[1728];   // this-step pooled layer1 events (ci*144+py*12+px)
    __shared__ unsigned short ev2[1024];   // this-step pooled layer2 events (NHWC flat idx)
    __shared__ unsigned int pm1[54];       // pooled-fired bitmask layer1
    __shared__ unsigned int pm2[32];       // pooled-fired bitmask layer2
    __shared__ float v3[16];
    __shared__ float outt[16];
    __shared__ int evin_cnt;
    __shared__ int ev1_cnt;
    __shared__ int ev2_cnt;

    // ---- init ----
    for (int i = tid; i < 6912; i += 256) v1[i] = 0.0f;
    for (int i = tid; i < 4096; i += 256) v2[i] = 0.0f;
    for (int i = tid; i < 300; i += 256) w1s[i] = w1g[i];   // FIX: was `if (tid < 300)`
    if (tid < 54) pm1[tid] = 0u;
    if (tid < 32) pm2[tid] = 0u;
    if (tid < 10) { v3[tid] = 0.0f; outt[tid] = NOT_FIREDf; }
    if (tid == 0) { evin_cnt = 0; ev1_cnt = 0; ev2_cnt = 0; }
    for (int i = tid; i < 784; i += 256) {
        float p = img[bimg * 784 + i];
        p = fmaxf(p, 1e-5f);
        float lg = (float)log((double)p);            // correctly-rounded f32 log
        float s = -TC_INf * lg;
        s = fmaxf(s, 0.0f);
        s = ceilf(s);
        int si = (int)fminf(s, 60000.0f);
        stin[i] = (unsigned short)si;
    }

    // per-slot channel biases (layer1: 27 slots of stride 256)
    float bias1v[27];
#pragma unroll
    for (int j = 0; j < 27; ++j) bias1v[j] = b1g[(tid + 256 * j) / 576];
    const float bias2v = b2g[lane];                      // all 16 layer2 slots share co = tid&63
    const float bias3v = (tid < 10) ? b3g[tid] : 0.0f;

    __syncthreads();

    for (int t = 0; t < 80; ++t) {
        const float tf = (float)t;
        const float xa = (0.0f - tf) / 20.0f;            // f32 arg, matching ref rounding
        const float th = (float)exp((double)xa);         // correctly-rounded f32 exp

        // ---- A: scan input spike times for this step ----
        for (int i = tid; i < 784; i += 256) {
            if ((int)stin[i] == t) {
                int pos = atomicAdd(&evin_cnt, 1);
                evin[pos] = (unsigned short)i;
            }
        }
        __syncthreads();

        // ---- B: scatter input events into v1 (wave-cooperative) ----
        {
            const int ne = evin_cnt;
            for (int e = wv; e < ne; e += 4) {
                const int p = evin[e];
                const int py = p / 28;
                const int px = p - py * 28;
#pragma unroll
                for (int base = 0; base < 5; ++base) {
                    int item = lane + base * 64;        // item over 12*25 = 300 (c,ky,kx)
                    if (item < 300) {
                        int c = item / 25;
                        int k = item - c * 25;
                        int ky = k / 5;
                        int kx = k - ky * 5;
                        int oy = py - ky;
                        int ox = px - kx;
                        if ((unsigned)oy < 24u && (unsigned)ox < 24u)
                            atomicAdd(&v1[c * 576 + oy * 24 + ox], w1s[item]);
                    }
                }
            }
        }
        __syncthreads();

        // ---- C: layer1 bias add + threshold check + pool dedup ----
        if (tid == 0) evin_cnt = 0;
#pragma unroll
        for (int j = 0; j < 27; ++j) {
            const int idx = tid + 256 * j;
            const float v = v1[idx] + bias1v[j];         // stepwise bias, matches ref order
            const bool fire = (v >= th);
            v1[idx] = fire ? -__builtin_inff() : v;      // fired: never again
            if (fire) {
                int c = idx / 576;
                int rem = idx - c * 576;
                int y = rem / 24;
                int x = rem - y * 24;
                int p = c * 144 + (y >> 1) * 12 + (x >> 1);
                unsigned int bit = 1u << (p & 31);
                unsigned int old = atomicOr(&pm1[p >> 5], bit);
                if (!(old & bit)) {
                    int pos = atomicAdd(&ev1_cnt, 1);
                    ev1[pos] = (unsigned short)p;
                }
            }
        }
        __syncthreads();

        // ---- D: conv2 scatter (pooled layer1 events -> v2) ----
        {
            const int ne = ev1_cnt;
            for (int e = wv; e < ne; e += 4) {
                const int p = ev1[e];
                const int ci = p / 144;
                const int rem = p - ci * 144;
                const int py = rem / 12;
                const int px = rem - py * 12;
                const float* wr = w2t + ci * 1600;
#pragma unroll
                for (int ky = 0; ky < 5; ++ky) {
                    const int oy = py - ky;
                    if ((unsigned)oy >= 8u) continue;
#pragma unroll
                    for (int kx = 0; kx < 5; ++kx) {
                        const int ox = px - kx;
                        if ((unsigned)ox >= 8u) continue;
                        const float wval = use_t
                            ? wr[(ky * 5 + kx) * 64 + lane]
                            : w2raw[(lane * 12 + ci) * 25 + ky * 5 + kx];
                        atomicAdd(&v2[(oy * 8 + ox) * 64 + lane], wval);
                    }
                }
            }
        }
        __syncthreads();

        // ---- E: layer2 bias add + threshold check + pool dedup ----
        if (tid == 0) ev1_cnt = 0;
        {
#pragma unroll
            for (int j = 0; j < 16; ++j) {
                const int idx = tid + 256 * j;
                const float v = v2[idx] + bias2v;        // stepwise bias
                const bool fire = (v >= th);
                v2[idx] = fire ? -__builtin_inff() : v;
                if (fire) {
                    const int pos = idx >> 6;            // oy*8+ox
                    const int oy = pos >> 3;
                    const int ox = pos & 7;
                    // pooled NHWC flat index = ph*256 + pw*64 + co
                    const int p = ((oy >> 1) * 4 + (ox >> 1)) * 64 + (idx & 63);
                    unsigned int bit = 1u << (p & 31);
                    unsigned int old = atomicOr(&pm2[p >> 5], bit);
                    if (!(old & bit)) {
                        int pos2 = atomicAdd(&ev2_cnt, 1);
                        ev2[pos2] = (unsigned short)p;
                    }
                }
            }
        }
        __syncthreads();

        // ---- F: fc scatter (pooled layer2 events -> v3) ----
        {
            const int tot = ev2_cnt * 10;
            for (int it = tid; it < tot; it += 256) {
                int e = it / 10;
                int j = it - e * 10;
                atomicAdd(&v3[j], fcw[(int)ev2[e] * 10 + j]);
            }
        }
        __syncthreads();

        // ---- G: output layer bias add + check ----
        if (tid < 10) {
            const float v = v3[tid] + bias3v;            // stepwise bias
            const bool fire = (v >= th);
            v3[tid] = fire ? -__builtin_inff() : v;
            if (fire) outt[tid] = tf;                    // first (and only) fire
        }
        if (tid == 0) ev2_cnt = 0;
        __syncthreads();
    }

    if (tid < 10) out[bimg * 10 + tid] = outt[tid];
}

extern "C" void kernel_launch(void* const* d_in, const int* in_sizes, int n_in,
                              void* d_out, int out_size, void* d_ws, size_t ws_size,
                              hipStream_t stream) {
    const float* img = (const float*)d_in[0];
    const float* w1  = (const float*)d_in[1];
    const float* b1  = (const float*)d_in[2];
    const float* w2  = (const float*)d_in[3];
    const float* b2  = (const float*)d_in[4];
    const float* fcw = (const float*)d_in[5];
    const float* b3  = (const float*)d_in[6];
    float* out = (float*)d_out;

    const int B = in_sizes[0] / (28 * 28);

    float* w2t = (float*)d_ws;
    const int use_t = (ws_size >= 19200 * sizeof(float)) ? 1 : 0;
    if (use_t) {
        hipLaunchKernelGGL(w2_transpose_kernel, dim3(75), dim3(256), 0, stream, w2, w2t);
    }
    hipLaunchKernelGGL(snn_sim_kernel, dim3(B), dim3(256), 0, stream,
                       img, w1, b1, b2, w2, w2t, fcw, b3, out, use_t);
}

// Round 3
// 6385.828 us; speedup vs baseline: 3.8474x; 3.8474x over previous
//
#include <hip/hip_runtime.h>
#include <math.h>

#define NOT_FIREDf 9999.0f

// Pre-transpose conv2 weights: w2t[((ci*5+ky)*5+kx)*64 + co] = w2[(co*12+ci)*25 + ky*5+kx]
__global__ void w2_transpose_kernel(const float* __restrict__ w2, float* __restrict__ w2t) {
    int idx = blockIdx.x * 256 + threadIdx.x;
    if (idx >= 19200) return;
    int co = idx & 63;
    int r = idx >> 6;          // 0..299 = ci*25 + k
    int ci = r / 25;
    int k = r - ci * 25;
    w2t[r * 64 + co] = w2[(co * 12 + ci) * 25 + k];
}

// v1 gather: add w1 row (12 channels, contiguous in w1s [k][c] layout) into regs
#define GATHER_V1(S, Y, X) do {                                              \
    const int dy_ = py - (Y), dx_ = px - (X);                                \
    if (((unsigned)dy_ < 5u) & ((unsigned)dx_ < 5u)) {                       \
        const float* wp_ = &w1s[(dy_ * 5 + dx_) * 12];                       \
        float4 a_  = *(const float4*)(wp_);                                  \
        float4 b_  = *(const float4*)(wp_ + 4);                              \
        float4 c_  = *(const float4*)(wp_ + 8);                              \
        v1r[S][0] += a_.x; v1r[S][1] += a_.y; v1r[S][2]  += a_.z; v1r[S][3]  += a_.w; \
        v1r[S][4] += b_.x; v1r[S][5] += b_.y; v1r[S][6]  += b_.z; v1r[S][7]  += b_.w; \
        v1r[S][8] += c_.x; v1r[S][9] += c_.y; v1r[S][10] += c_.z; v1r[S][11] += c_.w; \
    } } while (0)

// v1 threshold check + pool dedup for one owned pixel group
#define CHECK_V1(S, Y, X) do {                                               \
    _Pragma("unroll")                                                        \
    for (int c = 0; c < 12; ++c) {                                           \
        float v_ = v1r[S][c] + b1s[c];                                       \
        if (v_ >= th) {                                                      \
            v1r[S][c] = -__builtin_inff();                                   \
            int p_ = c * 144 + ((Y) >> 1) * 12 + ((X) >> 1);                 \
            unsigned bit_ = 1u << (p_ & 31);                                 \
            unsigned old_ = atomicOr(&pm1[p_ >> 5], bit_);                   \
            if (!(old_ & bit_)) {                                            \
                int pos_ = atomicAdd(&ev1_cnt[t & 1], 1);                    \
                ev1[pos_] = (unsigned short)p_;                              \
            }                                                                \
        } else v1r[S][c] = v_;                                               \
    } } while (0)

__launch_bounds__(256, 4)
__global__ void snn_sim_kernel(const float* __restrict__ img,
                               const float* __restrict__ w1g,
                               const float* __restrict__ b1g,
                               const float* __restrict__ b2g,
                               const float* __restrict__ w2raw,
                               const float* __restrict__ w2t,
                               const float* __restrict__ fcw,
                               const float* __restrict__ b3g,
                               float* __restrict__ out,
                               const int use_t) {
    const int bimg = blockIdx.x;
    const int tid  = threadIdx.x;
    const int lane = tid & 63;
    const int wv   = tid >> 6;   // 4 waves

    __shared__ __align__(16) float w1s[300];   // transposed: [k=ky*5+kx][c], 12 contiguous ch
    __shared__ float b1s[12];
    __shared__ float th_lds[80];
    __shared__ unsigned char  stin[784];       // input spike time per pixel (init only)
    __shared__ unsigned short evlist[784];     // t-sorted deterministic input event schedule
    __shared__ unsigned short off[81];         // per-t offsets into evlist
    __shared__ unsigned int   hist[80];
    __shared__ unsigned short ev1[1728];       // this-step pooled layer1 events
    __shared__ int            ev1_cnt[2];      // ping-pong (race-free reset)
    __shared__ unsigned int   pm1[54];         // pooled-fired bitmask layer1
    __shared__ unsigned int   pm2[32];         // pooled-fired bitmask layer2
    __shared__ unsigned int   e2list[1024];    // persistent: (t<<16) | nhwc_flat_idx
    __shared__ int            e2_cnt;

    // ---- init ----
    for (int i = tid; i < 300; i += 256) {
        int k = i / 12, c = i - k * 12;
        w1s[i] = w1g[c * 25 + k];              // [k][c] transposed
    }
    if (tid < 12) b1s[tid] = b1g[tid];
    if (tid < 80) {
        float xa = (0.0f - (float)tid) / 20.0f;          // f32 arg, ref rounding
        th_lds[tid] = (float)exp((double)xa);            // correctly-rounded f32 exp
        hist[tid] = 0u;
    }
    if (tid < 54) pm1[tid] = 0u;
    if (tid < 32) pm2[tid] = 0u;
    if (tid == 0) { ev1_cnt[0] = 0; ev1_cnt[1] = 0; e2_cnt = 0; }
    for (int i = tid; i < 784; i += 256) {
        float p = img[bimg * 784 + i];
        p = fmaxf(p, 1e-5f);
        float lg = (float)log((double)p);                // correctly-rounded f32 log
        float s = ceilf(fmaxf(-17.452274f * lg, 0.0f));
        stin[i] = (unsigned char)(int)fminf(s, 255.0f);
    }
    __syncthreads();
    for (int i = tid; i < 784; i += 256) {
        int t = stin[i];
        if (t < 80) atomicAdd(&hist[t], 1u);
    }
    __syncthreads();
    if (tid == 0) {
        unsigned int acc = 0;
        for (int t = 0; t < 80; ++t) { off[t] = (unsigned short)acc; acc += hist[t]; }
        off[80] = (unsigned short)acc;
    }
    __syncthreads();
    if (tid < 80) {                            // deterministic, pixel-order fill per t-bin
        int k = off[tid];
        for (int i = 0; i < 784; ++i)
            if ((int)stin[i] == tid) evlist[k++] = (unsigned short)i;
    }

    // ---- register state ----
    float v1r[3][12];                          // owned conv1 pixels: tid, tid+256, tid+512(<64)
#pragma unroll
    for (int s = 0; s < 3; ++s)
#pragma unroll
        for (int c = 0; c < 12; ++c) v1r[s][c] = 0.0f;
    float v2r[16];                             // owned conv2 slots: pos = wv*16+jj, co = lane
#pragma unroll
    for (int j = 0; j < 16; ++j) v2r[j] = 0.0f;

    const int y0 = tid / 24,         x0 = tid - y0 * 24;
    const int p1i = tid + 256;
    const int y1 = p1i / 24,         x1 = p1i - y1 * 24;
    const int has2 = (tid < 64);
    const int p2i = tid + 512;
    const int y2 = p2i / 24,         x2 = p2i - y2 * 24;
    const float b2v = b2g[lane];
    const int oyb = wv * 2;                    // v2 rows owned: oyb, oyb+1

    __syncthreads();

    // ---- time loop: 2 barriers/step ----
    for (int t = 0; t < 80; ++t) {
        const float th = th_lds[t];

        // phase 1: gather input events into v1 regs, then check + pool-dedup
        {
            const int e0 = off[t], e1 = off[t + 1];
            for (int e = e0; e < e1; ++e) {
                const int pix = evlist[e];     // LDS broadcast
                const int py = pix / 28;
                const int px = pix - py * 28;
                GATHER_V1(0, y0, x0);
                GATHER_V1(1, y1, x1);
                if (has2) GATHER_V1(2, y2, x2);
            }
        }
        CHECK_V1(0, y0, x0);
        CHECK_V1(1, y1, x1);
        if (has2) CHECK_V1(2, y2, x2);
        __syncthreads();                       // B1: ev1 complete

        // phase 2: gather layer1 pooled events into v2 regs, then check + log layer2 events
        const int ne1 = ev1_cnt[t & 1];
        if (tid == 0) ev1_cnt[(t + 1) & 1] = 0;   // safe: other buffer, bracketed by barriers
        for (int e = 0; e < ne1; ++e) {
            const int p  = ev1[e];             // LDS broadcast
            const int ci = p / 144;
            const int rm = p - ci * 144;
            const int py = rm / 12;
            const int px = rm - py * 12;
            const float* wrow = use_t ? (w2t + ci * 1600 + lane)
                                      : (w2raw + lane * 300 + ci * 25);
            const int imul = use_t ? 64 : 1;
#pragma unroll
            for (int jj = 0; jj < 16; ++jj) {  // wave-uniform window tests, coalesced loads
                const int oy = oyb + (jj >> 3);
                const int ox = jj & 7;
                const int dy = py - oy, dx = px - ox;
                if (((unsigned)dy < 5u) & ((unsigned)dx < 5u))
                    v2r[jj] += wrow[(dy * 5 + dx) * imul];
            }
        }
#pragma unroll
        for (int jj = 0; jj < 16; ++jj) {
            float v = v2r[jj] + b2v;
            if (v >= th) {
                v2r[jj] = -__builtin_inff();
                const int oy = oyb + (jj >> 3), ox = jj & 7;
                const int p2 = ((oy >> 1) * 4 + (ox >> 1)) * 64 + lane;  // NHWC flat
                unsigned bit = 1u << (p2 & 31);
                unsigned old = atomicOr(&pm2[p2 >> 5], bit);
                if (!(old & bit)) {
                    int pos = atomicAdd(&e2_cnt, 1);
                    e2list[pos] = ((unsigned)t << 16) | (unsigned)p2;
                }
            } else v2r[jj] = v;
        }
        __syncthreads();                       // B2: e2 appends done; ev1 reusable
    }

    // ---- output layer: replay t-sorted layer2 event log (no network feedback) ----
    if (tid < 10) {
        const int n2 = e2_cnt;
        const float b3v = b3g[tid];
        float v = 0.0f;
        float ot = NOT_FIREDf;
        int ptr = 0;
        for (int t = 0; t < 80; ++t) {
            float acc = 0.0f;
            while (ptr < n2 && (int)(e2list[ptr] >> 16) == t) {
                acc += fcw[(e2list[ptr] & 0xFFFFu) * 10 + tid];
                ++ptr;
            }
            v += acc + b3v;
            if (ot == NOT_FIREDf && v >= th_lds[t]) ot = (float)t;
        }
        out[bimg * 10 + tid] = ot;
    }
}

extern "C" void kernel_launch(void* const* d_in, const int* in_sizes, int n_in,
                              void* d_out, int out_size, void* d_ws, size_t ws_size,
                              hipStream_t stream) {
    const float* img = (const float*)d_in[0];
    const float* w1  = (const float*)d_in[1];
    const float* b1  = (const float*)d_in[2];
    const float* w2  = (const float*)d_in[3];
    const float* b2  = (const float*)d_in[4];
    const float* fcw = (const float*)d_in[5];
    const float* b3  = (const float*)d_in[6];
    float* out = (float*)d_out;

    const int B = in_sizes[0] / (28 * 28);

    float* w2t = (float*)d_ws;
    const int use_t = (ws_size >= 19200 * sizeof(float)) ? 1 : 0;
    if (use_t) {
        hipLaunchKernelGGL(w2_transpose_kernel, dim3(75), dim3(256), 0, stream, w2, w2t);
    }
    hipLaunchKernelGGL(snn_sim_kernel, dim3(B), dim3(256), 0, stream,
                       img, w1, b1, b2, w2, w2t, fcw, b3, out, use_t);
}